// Round 2
// baseline (1620.283 us; speedup 1.0000x reference)
//
#include <hip/hip_runtime.h>

// R1: identical to R0 baseline — both prior rounds failed GPU acquisition,
// so no counters exist to justify a change. Baseline attempt #3.

#define N_NODES 100000
#define N_EDGES 800000
#define D 128
#define BN_EPS 1e-5f

// ---------------- edge-index dtype hedge (int32 vs int64) ----------------
// Reference says int64; harness doc says int32. Detect on-device: if the
// high 32-bit word of the first 2048 entries is always 0, it's int64.
__global__ void detect_i64(const unsigned int* ei, int* flag) {
    __shared__ int nonzero;
    if (threadIdx.x == 0) nonzero = 0;
    __syncthreads();
    int local = 0;
    for (int i = threadIdx.x; i < 2048; i += 256)
        if (ei[2 * i + 1] != 0u) local = 1;
    if (local) atomicOr(&nonzero, 1);
    __syncthreads();
    if (threadIdx.x == 0) *flag = (nonzero == 0) ? 1 : 0;  // 1 => int64
}

__device__ __forceinline__ int edge_at(const void* ei, int is64, long long pos) {
    if (is64) return (int)((const long long*)ei)[pos];
    return ((const int*)ei)[pos];
}

// ---------------- degree ----------------
__global__ void count_deg(const void* ei, const int* __restrict__ flag,
                          float* __restrict__ deg) {
    int is64 = *flag;
    for (int i = blockIdx.x * blockDim.x + threadIdx.x; i < N_EDGES;
         i += gridDim.x * blockDim.x) {
        int d = edge_at(ei, is64, (long long)N_EDGES + i);
        atomicAdd(&deg[d], 1.0f);
    }
}

// dis = rsqrt(deg + 1)  (+1 = self loop)
__global__ void rsqrt_deg(const float* __restrict__ deg, float* __restrict__ dis) {
    int i = blockIdx.x * blockDim.x + threadIdx.x;
    if (i < N_NODES) dis[i] = rsqrtf(deg[i] + 1.0f);
}

// ---------------- GEMM h = x @ W (fp32, LDS-tiled) ----------------
// block: 256 threads, 64 rows x 128 cols; W staged in 64-row K-chunks.
// LDS = 32KB (A) + 32KB (W chunk) = 64KB -> 2 blocks/CU.
__global__ __launch_bounds__(256) void gemm_xw(const float* __restrict__ x,
                                               const float* __restrict__ Wm,
                                               float* __restrict__ h) {
    __shared__ float As[64 * 128];
    __shared__ float Ws[64 * 128];
    int tid = threadIdx.x;
    int row0 = blockIdx.x * 64;

    const float4* x4 = (const float4*)x;
    float4* A4 = (float4*)As;
#pragma unroll
    for (int i = 0; i < 8; ++i) {
        int idx = tid + i * 256;              // 0..2047 float4s
        int r = idx >> 5;                     // 32 float4 per row
        int gr = row0 + r;
        A4[idx] = (gr < N_NODES) ? x4[(size_t)gr * 32 + (idx & 31)]
                                 : make_float4(0.f, 0.f, 0.f, 0.f);
    }

    int tx = tid & 31;   // col group: cols tx*4 .. tx*4+3
    int ty = tid >> 5;   // row group: rows ty*8 .. ty*8+7
    float acc[8][4] = {};
    const float* Arow = &As[ty * 8 * 128];
    const float4* W4 = (const float4*)Wm;
    float4* Ws4 = (float4*)Ws;

    for (int kc = 0; kc < 128; kc += 64) {
        __syncthreads();  // protects Ws reuse; also covers initial A load
#pragma unroll
        for (int i = 0; i < 8; ++i) {
            int idx = tid + i * 256;          // 0..2047 float4s of the chunk
            Ws4[idx] = W4[kc * 32 + idx];
        }
        __syncthreads();
#pragma unroll 8
        for (int k = 0; k < 64; ++k) {
            float4 w = ((const float4*)&Ws[k * 128])[tx];
#pragma unroll
            for (int r = 0; r < 8; ++r) {
                float a = Arow[r * 128 + kc + k];
                acc[r][0] = fmaf(a, w.x, acc[r][0]);
                acc[r][1] = fmaf(a, w.y, acc[r][1]);
                acc[r][2] = fmaf(a, w.z, acc[r][2]);
                acc[r][3] = fmaf(a, w.w, acc[r][3]);
            }
        }
    }

#pragma unroll
    for (int r = 0; r < 8; ++r) {
        int gr = row0 + ty * 8 + r;
        if (gr < N_NODES)
            ((float4*)&h[(size_t)gr * 128])[tx] =
                make_float4(acc[r][0], acc[r][1], acc[r][2], acc[r][3]);
    }
}

// ---------------- edge scatter: agg[dst] += h[src] * dis[src]*dis[dst] ----------------
// 32 lanes per edge, float4 per lane; 8 edges per 256-thread block.
__global__ __launch_bounds__(256) void scatter_edges(const void* ei,
                                                     const int* __restrict__ flag,
                                                     const float* __restrict__ dis,
                                                     const float* __restrict__ h,
                                                     float* __restrict__ agg) {
    int is64 = *flag;
    int e = blockIdx.x * 8 + (threadIdx.x >> 5);
    if (e >= N_EDGES) return;
    int lane = threadIdx.x & 31;
    int s = edge_at(ei, is64, e);
    int d = edge_at(ei, is64, (long long)N_EDGES + e);
    float coef = dis[s] * dis[d];
    float4 v = ((const float4*)(h + (size_t)s * 128))[lane];
    float* o = agg + (size_t)d * 128 + (size_t)lane * 4;
    atomicAdd(o + 0, v.x * coef);
    atomicAdd(o + 1, v.y * coef);
    atomicAdd(o + 2, v.z * coef);
    atomicAdd(o + 3, v.w * coef);
}

// ---------------- self-loop add + column stats ----------------
// agg[r][c] += h[r][c] / deg_total[r]; accumulate per-column sum / sumsq.
__global__ __launch_bounds__(256) void stats_selfloop(const float* __restrict__ h,
                                                      const float* __restrict__ dis,
                                                      float* __restrict__ agg,
                                                      float* __restrict__ colsum,
                                                      float* __restrict__ colsumsq) {
    __shared__ float s1[256], s2[256];
    int tid = threadIdx.x;
    int c = tid & 127;
    int rhalf = tid >> 7;  // 0 or 1
    float sum = 0.f, sumsq = 0.f;
    for (int r2 = blockIdx.x; r2 < N_NODES / 2; r2 += gridDim.x) {
        int r = r2 * 2 + rhalf;
        size_t idx = (size_t)r * 128 + c;
        float ds = dis[r];
        float v = agg[idx] + h[idx] * (ds * ds);
        agg[idx] = v;
        sum += v;
        sumsq += v * v;
    }
    s1[tid] = sum;
    s2[tid] = sumsq;
    __syncthreads();
    if (tid < 128) {
        atomicAdd(&colsum[c], s1[tid] + s1[tid + 128]);
        atomicAdd(&colsumsq[c], s2[tid] + s2[tid + 128]);
    }
}

// ---------------- BN params (b cancels exactly; gamma/beta applied) ----------------
__global__ void finalize_bn(const float* __restrict__ colsum,
                            const float* __restrict__ colsumsq,
                            const float* __restrict__ gamma,
                            const float* __restrict__ beta,
                            float* __restrict__ scale, float* __restrict__ shift) {
    int c = threadIdx.x;
    float mean = colsum[c] * (1.0f / N_NODES);
    float var = colsumsq[c] * (1.0f / N_NODES) - mean * mean;
    float sc = gamma[c] * rsqrtf(var + BN_EPS);
    scale[c] = sc;
    shift[c] = beta[c] - mean * sc;
}

// ---------------- normalize + ReLU (in place on d_out) ----------------
__global__ __launch_bounds__(256) void normalize_relu(float* __restrict__ out,
                                                      const float* __restrict__ scale,
                                                      const float* __restrict__ shift) {
    const int total = N_NODES * 32;  // float4 count
    float4* o4 = (float4*)out;
    const float4* sc4 = (const float4*)scale;
    const float4* sh4 = (const float4*)shift;
    for (int i = blockIdx.x * blockDim.x + threadIdx.x; i < total;
         i += gridDim.x * blockDim.x) {
        int cg = i & 31;
        float4 v = o4[i];
        float4 sc = sc4[cg];
        float4 sh = sh4[cg];
        v.x = fmaxf(fmaf(v.x, sc.x, sh.x), 0.f);
        v.y = fmaxf(fmaf(v.y, sc.y, sh.y), 0.f);
        v.z = fmaxf(fmaf(v.z, sc.z, sh.z), 0.f);
        v.w = fmaxf(fmaf(v.w, sc.w, sh.w), 0.f);
        o4[i] = v;
    }
}

extern "C" void kernel_launch(void* const* d_in, const int* in_sizes, int n_in,
                              void* d_out, int out_size, void* d_ws, size_t ws_size,
                              hipStream_t stream) {
    const float* x = (const float*)d_in[0];
    const float* Wm = (const float*)d_in[1];
    // d_in[2] = b : cancels exactly in BatchNorm -> unused
    const float* gamma = (const float*)d_in[3];
    const float* beta = (const float*)d_in[4];
    const void* ei = d_in[5];

    float* out = (float*)d_out;

    float* h = (float*)d_ws;                       // N*D floats (51.2 MB)
    float* deg = h + (size_t)N_NODES * D;          // N floats
    float* dis = deg + N_NODES;                    // N floats
    float* colsum = dis + N_NODES;                 // 128
    float* colsumsq = colsum + 128;                // 128
    float* scale = colsumsq + 128;                 // 128
    float* shift = scale + 128;                    // 128
    int* flag = (int*)(shift + 128);               // 1

    // zero agg (lives in d_out), deg, and the stats accumulators
    hipMemsetAsync(out, 0, (size_t)N_NODES * D * sizeof(float), stream);
    hipMemsetAsync(deg, 0, (size_t)N_NODES * sizeof(float), stream);
    hipMemsetAsync(colsum, 0, 256 * sizeof(float), stream);

    detect_i64<<<1, 256, 0, stream>>>((const unsigned int*)ei, flag);
    count_deg<<<2048, 256, 0, stream>>>(ei, flag, deg);
    rsqrt_deg<<<(N_NODES + 255) / 256, 256, 0, stream>>>(deg, dis);
    gemm_xw<<<(N_NODES + 63) / 64, 256, 0, stream>>>(x, Wm, h);
    scatter_edges<<<N_EDGES / 8, 256, 0, stream>>>(ei, flag, dis, h, out);
    stats_selfloop<<<1024, 256, 0, stream>>>(h, dis, out, colsum, colsumsq);
    finalize_bn<<<1, 128, 0, stream>>>(colsum, colsumsq, gamma, beta, scale, shift);
    normalize_relu<<<2048, 256, 0, stream>>>(out, scale, shift);
}

// Round 3
// 402.275 us; speedup vs baseline: 4.0278x; 4.0278x over previous
//
#include <hip/hip_runtime.h>

// R3: kill the fp32 atomic scatter (1347us, WRITE_SIZE=1.6GB) via CSR gather.
// Algebraic restructure: segment_sum(norm * (xW)[src]) == segment_sum(norm * x[src]) @ W
// -> gather x first, then one in-place GEMM on d_out with fused BN column stats.

#define N_NODES 100000
#define N_EDGES 800000
#define D 128
#define BN_EPS 1e-5f
#define SCAN_NB 98  // ceil(100000/1024)

// ---------------- edge-index dtype hedge (int32 vs int64) ----------------
__global__ void detect_i64(const unsigned int* ei, int* flag) {
    __shared__ int nonzero;
    if (threadIdx.x == 0) nonzero = 0;
    __syncthreads();
    int local = 0;
    for (int i = threadIdx.x; i < 2048; i += 256)
        if (ei[2 * i + 1] != 0u) local = 1;
    if (local) atomicOr(&nonzero, 1);
    __syncthreads();
    if (threadIdx.x == 0) *flag = (nonzero == 0) ? 1 : 0;  // 1 => int64
}

__device__ __forceinline__ int edge_at(const void* ei, int is64, long long pos) {
    if (is64) return (int)((const long long*)ei)[pos];
    return ((const int*)ei)[pos];
}

// ---------------- degree histogram (int atomics) ----------------
__global__ void count_deg_i(const void* ei, const int* __restrict__ flag,
                            int* __restrict__ deg) {
    int is64 = *flag;
    for (int i = blockIdx.x * blockDim.x + threadIdx.x; i < N_EDGES;
         i += gridDim.x * blockDim.x) {
        int d = edge_at(ei, is64, (long long)N_EDGES + i);
        atomicAdd(&deg[d], 1);
    }
}

// ---------------- 3-kernel exclusive scan over deg -> rp ----------------
// scan1: each 256-thread block scans 1024 elements (4/thread).
__global__ __launch_bounds__(256) void scan1(const int* __restrict__ deg,
                                             int* __restrict__ rp,
                                             int* __restrict__ bsum) {
    __shared__ int wsum[4];
    int tid = threadIdx.x;
    int base = blockIdx.x * 1024;
    int v[4];
#pragma unroll
    for (int i = 0; i < 4; ++i) {
        int idx = base + tid * 4 + i;
        v[i] = (idx < N_NODES) ? deg[idx] : 0;
    }
    int tsum = v[0] + v[1] + v[2] + v[3];
    int lane = tid & 63;
    int incl = tsum;
#pragma unroll
    for (int off = 1; off < 64; off <<= 1) {
        int n = __shfl_up(incl, off, 64);
        if (lane >= off) incl += n;
    }
    int wid = tid >> 6;
    if (lane == 63) wsum[wid] = incl;
    __syncthreads();
    int woff = 0;
    for (int w = 0; w < wid; ++w) woff += wsum[w];
    int run = woff + incl - tsum;  // exclusive prefix for this thread
#pragma unroll
    for (int i = 0; i < 4; ++i) {
        int idx = base + tid * 4 + i;
        if (idx < N_NODES) rp[idx] = run;
        run += v[i];
    }
    if (tid == 255) bsum[blockIdx.x] = woff + incl;  // block total
}

// scan2: exclusive scan of the 98 block sums (in LDS); also rp[N] = E.
__global__ void scan2(int* __restrict__ bsum, int* __restrict__ rp) {
    __shared__ int s[128];
    int t = threadIdx.x;
    if (t < SCAN_NB) s[t] = bsum[t];
    __syncthreads();
    if (t == 0) {
        int run = 0;
        for (int i = 0; i < SCAN_NB; ++i) { int x = s[i]; s[i] = run; run += x; }
        rp[N_NODES] = N_EDGES;
    }
    __syncthreads();
    if (t < SCAN_NB) bsum[t] = s[t];
}

// scan3: add block offsets (in place), copy to fill ptr, compute dis.
__global__ void scan3(int* __restrict__ rp, const int* __restrict__ bsum,
                      int* __restrict__ fp, const int* __restrict__ deg,
                      float* __restrict__ dis) {
    int idx = blockIdx.x * 256 + threadIdx.x;
    if (idx < N_NODES) {
        int v = rp[idx] + bsum[idx >> 10];
        rp[idx] = v;
        fp[idx] = v;
        dis[idx] = rsqrtf((float)deg[idx] + 1.0f);  // +1 self loop
    }
}

// ---------------- bucket fill: ebuf[rp[d]..] = src ids ----------------
__global__ void fill_csr(const void* ei, const int* __restrict__ flag,
                         int* __restrict__ fp, int* __restrict__ ebuf) {
    int is64 = *flag;
    for (int e = blockIdx.x * blockDim.x + threadIdx.x; e < N_EDGES;
         e += gridDim.x * blockDim.x) {
        int s = edge_at(ei, is64, e);
        int d = edge_at(ei, is64, (long long)N_EDGES + e);
        int pos = atomicAdd(&fp[d], 1);
        ebuf[pos] = s;
    }
}

// ---------------- gather: aggx[d] = sum_e dis[s]*dis[d]*x[s] + dis[d]^2*x[d] ----------------
// one 64-lane wave per node, float2 per lane = one 512B row per load.
__global__ __launch_bounds__(256) void gather_x(const int* __restrict__ rp,
                                                const int* __restrict__ ebuf,
                                                const float* __restrict__ dis,
                                                const float* __restrict__ x,
                                                float* __restrict__ aggx) {
    int lane = threadIdx.x & 63;
    int wid = threadIdx.x >> 6;
    const float2* x2 = (const float2*)x;
    for (int node = blockIdx.x * 4 + wid; node < N_NODES;
         node += gridDim.x * 4) {
        int beg = rp[node], end = rp[node + 1];
        float dd = dis[node];
        float a0 = 0.f, a1 = 0.f;
        for (int j = beg; j < end; ++j) {
            int s = ebuf[j];
            float coef = dis[s] * dd;
            float2 v = x2[(size_t)s * 64 + lane];
            a0 = fmaf(v.x, coef, a0);
            a1 = fmaf(v.y, coef, a1);
        }
        float2 xv = x2[(size_t)node * 64 + lane];
        float c2 = dd * dd;
        a0 = fmaf(xv.x, c2, a0);
        a1 = fmaf(xv.y, c2, a1);
        ((float2*)aggx)[(size_t)node * 64 + lane] = make_float2(a0, a1);
    }
}

// ---------------- in-place GEMM d_out = d_out @ W, fused column stats ----------------
// Race-free in place: each block stages its own 64x128 tile to LDS before writing.
__global__ __launch_bounds__(256) void gemm_stats(float* __restrict__ ax,
                                                  const float* __restrict__ Wm,
                                                  float* __restrict__ colsum,
                                                  float* __restrict__ colsumsq) {
    __shared__ float As[64 * 128];
    __shared__ float Ws[64 * 128];
    int tid = threadIdx.x;
    int row0 = blockIdx.x * 64;

    const float4* a4 = (const float4*)ax;
    float4* A4 = (float4*)As;
#pragma unroll
    for (int i = 0; i < 8; ++i) {
        int idx = tid + i * 256;
        int r = idx >> 5;
        int gr = row0 + r;
        A4[idx] = (gr < N_NODES) ? a4[(size_t)gr * 32 + (idx & 31)]
                                 : make_float4(0.f, 0.f, 0.f, 0.f);
    }

    int tx = tid & 31;
    int ty = tid >> 5;
    float acc[8][4] = {};
    const float* Arow = &As[ty * 8 * 128];
    const float4* W4 = (const float4*)Wm;
    float4* Ws4 = (float4*)Ws;

    for (int kc = 0; kc < 128; kc += 64) {
        __syncthreads();
#pragma unroll
        for (int i = 0; i < 8; ++i) {
            int idx = tid + i * 256;
            Ws4[idx] = W4[kc * 32 + idx];
        }
        __syncthreads();
#pragma unroll 8
        for (int k = 0; k < 64; ++k) {
            float4 w = ((const float4*)&Ws[k * 128])[tx];
#pragma unroll
            for (int r = 0; r < 8; ++r) {
                float a = Arow[r * 128 + kc + k];
                acc[r][0] = fmaf(a, w.x, acc[r][0]);
                acc[r][1] = fmaf(a, w.y, acc[r][1]);
                acc[r][2] = fmaf(a, w.z, acc[r][2]);
                acc[r][3] = fmaf(a, w.w, acc[r][3]);
            }
        }
    }

    // write back (in place; rows beyond N guarded)
#pragma unroll
    for (int r = 0; r < 8; ++r) {
        int gr = row0 + ty * 8 + r;
        if (gr < N_NODES)
            ((float4*)&ax[(size_t)gr * 128])[tx] =
                make_float4(acc[r][0], acc[r][1], acc[r][2], acc[r][3]);
    }

    // fused BN column stats; padded rows have acc==0 (As zero-filled) -> contribute 0
    float ps[4] = {0.f, 0.f, 0.f, 0.f}, pq[4] = {0.f, 0.f, 0.f, 0.f};
#pragma unroll
    for (int r = 0; r < 8; ++r)
#pragma unroll
        for (int k = 0; k < 4; ++k) {
            float v = acc[r][k];
            ps[k] += v;
            pq[k] += v * v;
        }
    __syncthreads();  // all waves done with As/Ws -> reuse as reduce buffers
#pragma unroll
    for (int k = 0; k < 4; ++k) {
        Ws[ty * 128 + tx * 4 + k] = ps[k];
        As[ty * 128 + tx * 4 + k] = pq[k];
    }
    __syncthreads();
    if (tid < 128) {
        float s = 0.f, q = 0.f;
#pragma unroll
        for (int t = 0; t < 8; ++t) {
            s += Ws[t * 128 + tid];
            q += As[t * 128 + tid];
        }
        atomicAdd(&colsum[tid], s);
        atomicAdd(&colsumsq[tid], q);
    }
}

// ---------------- BN params (b cancels exactly in BatchNorm) ----------------
__global__ void finalize_bn(const float* __restrict__ colsum,
                            const float* __restrict__ colsumsq,
                            const float* __restrict__ gamma,
                            const float* __restrict__ beta,
                            float* __restrict__ scale, float* __restrict__ shift) {
    int c = threadIdx.x;
    float mean = colsum[c] * (1.0f / N_NODES);
    float var = colsumsq[c] * (1.0f / N_NODES) - mean * mean;
    float sc = gamma[c] * rsqrtf(var + BN_EPS);
    scale[c] = sc;
    shift[c] = beta[c] - mean * sc;
}

// ---------------- normalize + ReLU (in place on d_out) ----------------
__global__ __launch_bounds__(256) void normalize_relu(float* __restrict__ out,
                                                      const float* __restrict__ scale,
                                                      const float* __restrict__ shift) {
    const int total = N_NODES * 32;  // float4 count
    float4* o4 = (float4*)out;
    const float4* sc4 = (const float4*)scale;
    const float4* sh4 = (const float4*)shift;
    for (int i = blockIdx.x * blockDim.x + threadIdx.x; i < total;
         i += gridDim.x * blockDim.x) {
        int cg = i & 31;
        float4 v = o4[i];
        float4 sc = sc4[cg];
        float4 sh = sh4[cg];
        v.x = fmaxf(fmaf(v.x, sc.x, sh.x), 0.f);
        v.y = fmaxf(fmaf(v.y, sc.y, sh.y), 0.f);
        v.z = fmaxf(fmaf(v.z, sc.z, sh.z), 0.f);
        v.w = fmaxf(fmaf(v.w, sc.w, sh.w), 0.f);
        o4[i] = v;
    }
}

extern "C" void kernel_launch(void* const* d_in, const int* in_sizes, int n_in,
                              void* d_out, int out_size, void* d_ws, size_t ws_size,
                              hipStream_t stream) {
    const float* x = (const float*)d_in[0];
    const float* Wm = (const float*)d_in[1];
    // d_in[2] = b : cancels exactly in BatchNorm -> unused
    const float* gamma = (const float*)d_in[3];
    const float* beta = (const float*)d_in[4];
    const void* ei = d_in[5];

    float* out = (float*)d_out;  // holds agg_x, then agg, then final

    // workspace layout (~4.8 MB total)
    int* deg = (int*)d_ws;                  // N
    int* rp = deg + N_NODES;                // N+1
    int* fp = rp + N_NODES + 1;             // N
    int* bsum = fp + N_NODES;               // 128
    float* dis = (float*)(bsum + 128);      // N
    float* colsum = dis + N_NODES;          // 128
    float* colsumsq = colsum + 128;         // 128
    float* scale = colsumsq + 128;          // 128
    float* shift = scale + 128;             // 128
    int* flag = (int*)(shift + 128);        // 1 (padded)
    int* ebuf = flag + 64;                  // E

    hipMemsetAsync(deg, 0, (size_t)N_NODES * sizeof(int), stream);
    hipMemsetAsync(colsum, 0, 256 * sizeof(float), stream);

    detect_i64<<<1, 256, 0, stream>>>((const unsigned int*)ei, flag);
    count_deg_i<<<2048, 256, 0, stream>>>(ei, flag, deg);
    scan1<<<SCAN_NB, 256, 0, stream>>>(deg, rp, bsum);
    scan2<<<1, 128, 0, stream>>>(bsum, rp);
    scan3<<<(N_NODES + 255) / 256, 256, 0, stream>>>(rp, bsum, fp, deg, dis);
    fill_csr<<<2048, 256, 0, stream>>>(ei, flag, fp, ebuf);
    gather_x<<<2048, 256, 0, stream>>>(rp, ebuf, dis, x, out);
    gemm_stats<<<(N_NODES + 63) / 64, 256, 0, stream>>>(out, Wm, colsum, colsumsq);
    finalize_bn<<<1, 128, 0, stream>>>(colsum, colsumsq, gamma, beta, scale, shift);
    normalize_relu<<<2048, 256, 0, stream>>>(out, scale, shift);
}

// Round 5
// 372.174 us; speedup vs baseline: 4.3536x; 1.0809x over previous
//
#include <hip/hip_runtime.h>

// R5: identical to R4 — it never ran (GPU acquisition timeout), so the
// (src,coef)-packing + 4-deep gather pipeline + GEMM k-chunking diff is
// still unmeasured. Measurement attempt #2 for that diff.

#define N_NODES 100000
#define N_EDGES 800000
#define D 128
#define BN_EPS 1e-5f
#define SCAN_NB 98  // ceil(100000/1024)

// ---------------- edge-index dtype hedge (int32 vs int64) ----------------
__global__ void detect_i64(const unsigned int* ei, int* flag) {
    __shared__ int nonzero;
    if (threadIdx.x == 0) nonzero = 0;
    __syncthreads();
    int local = 0;
    for (int i = threadIdx.x; i < 2048; i += 256)
        if (ei[2 * i + 1] != 0u) local = 1;
    if (local) atomicOr(&nonzero, 1);
    __syncthreads();
    if (threadIdx.x == 0) *flag = (nonzero == 0) ? 1 : 0;  // 1 => int64
}

__device__ __forceinline__ int edge_at(const void* ei, int is64, long long pos) {
    if (is64) return (int)((const long long*)ei)[pos];
    return ((const int*)ei)[pos];
}

// ---------------- degree histogram (int atomics) ----------------
__global__ void count_deg_i(const void* ei, const int* __restrict__ flag,
                            int* __restrict__ deg) {
    int is64 = *flag;
    for (int i = blockIdx.x * blockDim.x + threadIdx.x; i < N_EDGES;
         i += gridDim.x * blockDim.x) {
        int d = edge_at(ei, is64, (long long)N_EDGES + i);
        atomicAdd(&deg[d], 1);
    }
}

// ---------------- 3-kernel exclusive scan over deg -> rp ----------------
__global__ __launch_bounds__(256) void scan1(const int* __restrict__ deg,
                                             int* __restrict__ rp,
                                             int* __restrict__ bsum) {
    __shared__ int wsum[4];
    int tid = threadIdx.x;
    int base = blockIdx.x * 1024;
    int v[4];
#pragma unroll
    for (int i = 0; i < 4; ++i) {
        int idx = base + tid * 4 + i;
        v[i] = (idx < N_NODES) ? deg[idx] : 0;
    }
    int tsum = v[0] + v[1] + v[2] + v[3];
    int lane = tid & 63;
    int incl = tsum;
#pragma unroll
    for (int off = 1; off < 64; off <<= 1) {
        int n = __shfl_up(incl, off, 64);
        if (lane >= off) incl += n;
    }
    int wid = tid >> 6;
    if (lane == 63) wsum[wid] = incl;
    __syncthreads();
    int woff = 0;
    for (int w = 0; w < wid; ++w) woff += wsum[w];
    int run = woff + incl - tsum;  // exclusive prefix for this thread
#pragma unroll
    for (int i = 0; i < 4; ++i) {
        int idx = base + tid * 4 + i;
        if (idx < N_NODES) rp[idx] = run;
        run += v[i];
    }
    if (tid == 255) bsum[blockIdx.x] = woff + incl;  // block total
}

__global__ void scan2(int* __restrict__ bsum, int* __restrict__ rp) {
    __shared__ int s[128];
    int t = threadIdx.x;
    if (t < SCAN_NB) s[t] = bsum[t];
    __syncthreads();
    if (t == 0) {
        int run = 0;
        for (int i = 0; i < SCAN_NB; ++i) { int x = s[i]; s[i] = run; run += x; }
        rp[N_NODES] = N_EDGES;
    }
    __syncthreads();
    if (t < SCAN_NB) bsum[t] = s[t];
}

__global__ void scan3(int* __restrict__ rp, const int* __restrict__ bsum,
                      int* __restrict__ fp, const int* __restrict__ deg,
                      float* __restrict__ dis) {
    int idx = blockIdx.x * 256 + threadIdx.x;
    if (idx < N_NODES) {
        int v = rp[idx] + bsum[idx >> 10];
        rp[idx] = v;
        fp[idx] = v;
        dis[idx] = rsqrtf((float)deg[idx] + 1.0f);  // +1 self loop
    }
}

// ---------------- bucket fill: eb[rp[d]..] = (src, dis[s]*dis[d]) ----------------
__global__ void fill_csr(const void* ei, const int* __restrict__ flag,
                         int* __restrict__ fp, const float* __restrict__ dis,
                         int2* __restrict__ eb) {
    int is64 = *flag;
    for (int e = blockIdx.x * blockDim.x + threadIdx.x; e < N_EDGES;
         e += gridDim.x * blockDim.x) {
        int s = edge_at(ei, is64, e);
        int d = edge_at(ei, is64, (long long)N_EDGES + e);
        float coef = dis[s] * dis[d];
        int pos = atomicAdd(&fp[d], 1);
        eb[pos] = make_int2(s, __float_as_int(coef));
    }
}

// ---------------- gather: aggx[d] = sum_e coef*x[s] + dis[d]^2*x[d] ----------------
// one 64-lane wave per node, float2 per lane; 4-deep edge pipeline.
__global__ __launch_bounds__(256) void gather_x(const int* __restrict__ rp,
                                                const int2* __restrict__ eb,
                                                const float* __restrict__ dis,
                                                const float* __restrict__ x,
                                                float* __restrict__ aggx) {
    int lane = threadIdx.x & 63;
    int wid = threadIdx.x >> 6;
    const float2* x2 = (const float2*)x;
    for (int node = blockIdx.x * 4 + wid; node < N_NODES;
         node += gridDim.x * 4) {
        int beg = rp[node], end = rp[node + 1];
        float dd = dis[node];
        float2 xv = x2[(size_t)node * 64 + lane];
        float c2 = dd * dd;
        float a0 = xv.x * c2, a1 = xv.y * c2;
        int j = beg;
        for (; j + 4 <= end; j += 4) {
            int2 e0 = eb[j], e1 = eb[j + 1], e2 = eb[j + 2], e3 = eb[j + 3];
            float2 v0 = x2[(size_t)e0.x * 64 + lane];
            float2 v1 = x2[(size_t)e1.x * 64 + lane];
            float2 v2 = x2[(size_t)e2.x * 64 + lane];
            float2 v3 = x2[(size_t)e3.x * 64 + lane];
            float c0 = __int_as_float(e0.y), c1 = __int_as_float(e1.y);
            float cc = __int_as_float(e2.y), c3 = __int_as_float(e3.y);
            a0 = fmaf(v0.x, c0, a0); a1 = fmaf(v0.y, c0, a1);
            a0 = fmaf(v1.x, c1, a0); a1 = fmaf(v1.y, c1, a1);
            a0 = fmaf(v2.x, cc, a0); a1 = fmaf(v2.y, cc, a1);
            a0 = fmaf(v3.x, c3, a0); a1 = fmaf(v3.y, c3, a1);
        }
        for (; j < end; ++j) {
            int2 e = eb[j];
            float2 v = x2[(size_t)e.x * 64 + lane];
            float c = __int_as_float(e.y);
            a0 = fmaf(v.x, c, a0); a1 = fmaf(v.y, c, a1);
        }
        ((float2*)aggx)[(size_t)node * 64 + lane] = make_float2(a0, a1);
    }
}

// ---------------- in-place GEMM d_out = d_out @ W, fused column stats ----------------
__global__ __launch_bounds__(256) void gemm_stats(float* __restrict__ ax,
                                                  const float* __restrict__ Wm,
                                                  float* __restrict__ colsum,
                                                  float* __restrict__ colsumsq) {
    __shared__ float As[64 * 128];
    __shared__ float Ws[64 * 128];
    int tid = threadIdx.x;
    int row0 = blockIdx.x * 64;

    const float4* a4 = (const float4*)ax;
    float4* A4 = (float4*)As;
#pragma unroll
    for (int i = 0; i < 8; ++i) {
        int idx = tid + i * 256;
        int r = idx >> 5;
        int gr = row0 + r;
        A4[idx] = (gr < N_NODES) ? a4[(size_t)gr * 32 + (idx & 31)]
                                 : make_float4(0.f, 0.f, 0.f, 0.f);
    }

    int tx = tid & 31;
    int ty = tid >> 5;
    float acc[8][4] = {};
    const float* Arow = &As[ty * 8 * 128];
    const float4* W4 = (const float4*)Wm;
    float4* Ws4 = (float4*)Ws;

    for (int kc = 0; kc < 128; kc += 64) {
        __syncthreads();
#pragma unroll
        for (int i = 0; i < 8; ++i) {
            int idx = tid + i * 256;
            Ws4[idx] = W4[kc * 32 + idx];
        }
        __syncthreads();
        for (int k4 = 0; k4 < 64; k4 += 4) {
            float4 a8[8];
#pragma unroll
            for (int r = 0; r < 8; ++r)
                a8[r] = *(const float4*)&Arow[r * 128 + kc + k4];
#pragma unroll
            for (int kk = 0; kk < 4; ++kk) {
                float4 w = ((const float4*)&Ws[(k4 + kk) * 128])[tx];
#pragma unroll
                for (int r = 0; r < 8; ++r) {
                    float av = (kk == 0) ? a8[r].x : (kk == 1) ? a8[r].y
                             : (kk == 2) ? a8[r].z : a8[r].w;
                    acc[r][0] = fmaf(av, w.x, acc[r][0]);
                    acc[r][1] = fmaf(av, w.y, acc[r][1]);
                    acc[r][2] = fmaf(av, w.z, acc[r][2]);
                    acc[r][3] = fmaf(av, w.w, acc[r][3]);
                }
            }
        }
    }

    // write back (in place; own tile staged already -> race-free)
#pragma unroll
    for (int r = 0; r < 8; ++r) {
        int gr = row0 + ty * 8 + r;
        if (gr < N_NODES)
            ((float4*)&ax[(size_t)gr * 128])[tx] =
                make_float4(acc[r][0], acc[r][1], acc[r][2], acc[r][3]);
    }

    // fused BN column stats; padded rows contribute 0
    float ps[4] = {0.f, 0.f, 0.f, 0.f}, pq[4] = {0.f, 0.f, 0.f, 0.f};
#pragma unroll
    for (int r = 0; r < 8; ++r)
#pragma unroll
        for (int k = 0; k < 4; ++k) {
            float v = acc[r][k];
            ps[k] += v;
            pq[k] += v * v;
        }
    __syncthreads();  // done with As/Ws -> reuse as reduce buffers
#pragma unroll
    for (int k = 0; k < 4; ++k) {
        Ws[ty * 128 + tx * 4 + k] = ps[k];
        As[ty * 128 + tx * 4 + k] = pq[k];
    }
    __syncthreads();
    if (tid < 128) {
        float s = 0.f, q = 0.f;
#pragma unroll
        for (int t = 0; t < 8; ++t) {
            s += Ws[t * 128 + tid];
            q += As[t * 128 + tid];
        }
        atomicAdd(&colsum[tid], s);
        atomicAdd(&colsumsq[tid], q);
    }
}

// ---------------- BN params (b cancels exactly in BatchNorm) ----------------
__global__ void finalize_bn(const float* __restrict__ colsum,
                            const float* __restrict__ colsumsq,
                            const float* __restrict__ gamma,
                            const float* __restrict__ beta,
                            float* __restrict__ scale, float* __restrict__ shift) {
    int c = threadIdx.x;
    float mean = colsum[c] * (1.0f / N_NODES);
    float var = colsumsq[c] * (1.0f / N_NODES) - mean * mean;
    float sc = gamma[c] * rsqrtf(var + BN_EPS);
    scale[c] = sc;
    shift[c] = beta[c] - mean * sc;
}

// ---------------- normalize + ReLU (in place on d_out) ----------------
__global__ __launch_bounds__(256) void normalize_relu(float* __restrict__ out,
                                                      const float* __restrict__ scale,
                                                      const float* __restrict__ shift) {
    const int total = N_NODES * 32;  // float4 count
    float4* o4 = (float4*)out;
    const float4* sc4 = (const float4*)scale;
    const float4* sh4 = (const float4*)shift;
    for (int i = blockIdx.x * blockDim.x + threadIdx.x; i < total;
         i += gridDim.x * blockDim.x) {
        int cg = i & 31;
        float4 v = o4[i];
        float4 sc = sc4[cg];
        float4 sh = sh4[cg];
        v.x = fmaxf(fmaf(v.x, sc.x, sh.x), 0.f);
        v.y = fmaxf(fmaf(v.y, sc.y, sh.y), 0.f);
        v.z = fmaxf(fmaf(v.z, sc.z, sh.z), 0.f);
        v.w = fmaxf(fmaf(v.w, sc.w, sh.w), 0.f);
        o4[i] = v;
    }
}

extern "C" void kernel_launch(void* const* d_in, const int* in_sizes, int n_in,
                              void* d_out, int out_size, void* d_ws, size_t ws_size,
                              hipStream_t stream) {
    const float* x = (const float*)d_in[0];
    const float* Wm = (const float*)d_in[1];
    // d_in[2] = b : cancels exactly in BatchNorm -> unused
    const float* gamma = (const float*)d_in[3];
    const float* beta = (const float*)d_in[4];
    const void* ei = d_in[5];

    float* out = (float*)d_out;  // holds agg_x, then final

    // workspace layout: eb first (8B aligned at base), then int/float arrays
    int2* eb = (int2*)d_ws;                 // E pairs (6.4 MB)
    int* deg = (int*)(eb + N_EDGES);        // N
    int* rp = deg + N_NODES;                // N+1
    int* fp = rp + N_NODES + 1;             // N
    int* bsum = fp + N_NODES;               // 128
    float* dis = (float*)(bsum + 128);      // N
    float* colsum = dis + N_NODES;          // 128
    float* colsumsq = colsum + 128;         // 128
    float* scale = colsumsq + 128;          // 128
    float* shift = scale + 128;             // 128
    int* flag = (int*)(shift + 128);        // 1

    hipMemsetAsync(deg, 0, (size_t)N_NODES * sizeof(int), stream);
    hipMemsetAsync(colsum, 0, 256 * sizeof(float), stream);

    detect_i64<<<1, 256, 0, stream>>>((const unsigned int*)ei, flag);
    count_deg_i<<<2048, 256, 0, stream>>>(ei, flag, deg);
    scan1<<<SCAN_NB, 256, 0, stream>>>(deg, rp, bsum);
    scan2<<<1, 128, 0, stream>>>(bsum, rp);
    scan3<<<(N_NODES + 255) / 256, 256, 0, stream>>>(rp, bsum, fp, deg, dis);
    fill_csr<<<2048, 256, 0, stream>>>(ei, flag, fp, dis, eb);
    gather_x<<<2048, 256, 0, stream>>>(rp, eb, dis, x, out);
    gemm_stats<<<(N_NODES + 63) / 64, 256, 0, stream>>>(out, Wm, colsum, colsumsq);
    finalize_bn<<<1, 128, 0, stream>>>(colsum, colsumsq, gamma, beta, scale, shift);
    normalize_relu<<<2048, 256, 0, stream>>>(out, scale, shift);
}

// Round 8
// 353.246 us; speedup vs baseline: 4.5868x; 1.0536x over previous
//
#include <hip/hip_runtime.h>

// R8: identical to R6/R7 — two consecutive acquisition timeouts; the
// 24KB-LDS k-chunked GEMM diff is still unmeasured. Attempt #3.

#define N_NODES 100000
#define N_EDGES 800000
#define D 128
#define BN_EPS 1e-5f
#define SCAN_NB 98  // ceil(100000/1024)
#define KC 32       // GEMM k-chunk

// ---------------- edge-index dtype hedge (int32 vs int64) ----------------
__global__ void detect_i64(const unsigned int* ei, int* flag) {
    __shared__ int nonzero;
    if (threadIdx.x == 0) nonzero = 0;
    __syncthreads();
    int local = 0;
    for (int i = threadIdx.x; i < 2048; i += 256)
        if (ei[2 * i + 1] != 0u) local = 1;
    if (local) atomicOr(&nonzero, 1);
    __syncthreads();
    if (threadIdx.x == 0) *flag = (nonzero == 0) ? 1 : 0;  // 1 => int64
}

__device__ __forceinline__ int edge_at(const void* ei, int is64, long long pos) {
    if (is64) return (int)((const long long*)ei)[pos];
    return ((const int*)ei)[pos];
}

// ---------------- degree histogram (int atomics) ----------------
__global__ void count_deg_i(const void* ei, const int* __restrict__ flag,
                            int* __restrict__ deg) {
    int is64 = *flag;
    for (int i = blockIdx.x * blockDim.x + threadIdx.x; i < N_EDGES;
         i += gridDim.x * blockDim.x) {
        int d = edge_at(ei, is64, (long long)N_EDGES + i);
        atomicAdd(&deg[d], 1);
    }
}

// ---------------- 3-kernel exclusive scan over deg -> rp ----------------
__global__ __launch_bounds__(256) void scan1(const int* __restrict__ deg,
                                             int* __restrict__ rp,
                                             int* __restrict__ bsum) {
    __shared__ int wsum[4];
    int tid = threadIdx.x;
    int base = blockIdx.x * 1024;
    int v[4];
#pragma unroll
    for (int i = 0; i < 4; ++i) {
        int idx = base + tid * 4 + i;
        v[i] = (idx < N_NODES) ? deg[idx] : 0;
    }
    int tsum = v[0] + v[1] + v[2] + v[3];
    int lane = tid & 63;
    int incl = tsum;
#pragma unroll
    for (int off = 1; off < 64; off <<= 1) {
        int n = __shfl_up(incl, off, 64);
        if (lane >= off) incl += n;
    }
    int wid = tid >> 6;
    if (lane == 63) wsum[wid] = incl;
    __syncthreads();
    int woff = 0;
    for (int w = 0; w < wid; ++w) woff += wsum[w];
    int run = woff + incl - tsum;  // exclusive prefix for this thread
#pragma unroll
    for (int i = 0; i < 4; ++i) {
        int idx = base + tid * 4 + i;
        if (idx < N_NODES) rp[idx] = run;
        run += v[i];
    }
    if (tid == 255) bsum[blockIdx.x] = woff + incl;  // block total
}

__global__ void scan2(int* __restrict__ bsum, int* __restrict__ rp) {
    __shared__ int s[128];
    int t = threadIdx.x;
    if (t < SCAN_NB) s[t] = bsum[t];
    __syncthreads();
    if (t == 0) {
        int run = 0;
        for (int i = 0; i < SCAN_NB; ++i) { int x = s[i]; s[i] = run; run += x; }
        rp[N_NODES] = N_EDGES;
    }
    __syncthreads();
    if (t < SCAN_NB) bsum[t] = s[t];
}

__global__ void scan3(int* __restrict__ rp, const int* __restrict__ bsum,
                      int* __restrict__ fp, const int* __restrict__ deg,
                      float* __restrict__ dis) {
    int idx = blockIdx.x * 256 + threadIdx.x;
    if (idx < N_NODES) {
        int v = rp[idx] + bsum[idx >> 10];
        rp[idx] = v;
        fp[idx] = v;
        dis[idx] = rsqrtf((float)deg[idx] + 1.0f);  // +1 self loop
    }
}

// ---------------- bucket fill: eb[rp[d]..] = (src, dis[s]*dis[d]) ----------------
__global__ void fill_csr(const void* ei, const int* __restrict__ flag,
                         int* __restrict__ fp, const float* __restrict__ dis,
                         int2* __restrict__ eb) {
    int is64 = *flag;
    for (int e = blockIdx.x * blockDim.x + threadIdx.x; e < N_EDGES;
         e += gridDim.x * blockDim.x) {
        int s = edge_at(ei, is64, e);
        int d = edge_at(ei, is64, (long long)N_EDGES + e);
        float coef = dis[s] * dis[d];
        int pos = atomicAdd(&fp[d], 1);
        eb[pos] = make_int2(s, __float_as_int(coef));
    }
}

// ---------------- gather: aggx[d] = sum_e coef*x[s] + dis[d]^2*x[d] ----------------
// one 64-lane wave per node, float2 per lane; 4-deep edge pipeline.
__global__ __launch_bounds__(256) void gather_x(const int* __restrict__ rp,
                                                const int2* __restrict__ eb,
                                                const float* __restrict__ dis,
                                                const float* __restrict__ x,
                                                float* __restrict__ aggx) {
    int lane = threadIdx.x & 63;
    int wid = threadIdx.x >> 6;
    const float2* x2 = (const float2*)x;
    for (int node = blockIdx.x * 4 + wid; node < N_NODES;
         node += gridDim.x * 4) {
        int beg = rp[node], end = rp[node + 1];
        float dd = dis[node];
        float2 xv = x2[(size_t)node * 64 + lane];
        float c2 = dd * dd;
        float a0 = xv.x * c2, a1 = xv.y * c2;
        int j = beg;
        for (; j + 4 <= end; j += 4) {
            int2 e0 = eb[j], e1 = eb[j + 1], e2 = eb[j + 2], e3 = eb[j + 3];
            float2 v0 = x2[(size_t)e0.x * 64 + lane];
            float2 v1 = x2[(size_t)e1.x * 64 + lane];
            float2 v2 = x2[(size_t)e2.x * 64 + lane];
            float2 v3 = x2[(size_t)e3.x * 64 + lane];
            float c0 = __int_as_float(e0.y), c1 = __int_as_float(e1.y);
            float cc = __int_as_float(e2.y), c3 = __int_as_float(e3.y);
            a0 = fmaf(v0.x, c0, a0); a1 = fmaf(v0.y, c0, a1);
            a0 = fmaf(v1.x, c1, a0); a1 = fmaf(v1.y, c1, a1);
            a0 = fmaf(v2.x, cc, a0); a1 = fmaf(v2.y, cc, a1);
            a0 = fmaf(v3.x, c3, a0); a1 = fmaf(v3.y, c3, a1);
        }
        for (; j < end; ++j) {
            int2 e = eb[j];
            float2 v = x2[(size_t)e.x * 64 + lane];
            float c = __int_as_float(e.y);
            a0 = fmaf(v.x, c, a0); a1 = fmaf(v.y, c, a1);
        }
        ((float2*)aggx)[(size_t)node * 64 + lane] = make_float2(a0, a1);
    }
}

// ---------------- in-place GEMM d_out = d_out @ W, fused column stats ----------------
// K-chunked both operands: As 8KB + Ws 16KB = 24KB LDS -> ~5 blocks/CU.
// In place race-free: block reads only its own 64 rows (all reads precede
// its writes; no other block touches them).
__global__ __launch_bounds__(256) void gemm_stats(float* __restrict__ ax,
                                                  const float* __restrict__ Wm,
                                                  float* __restrict__ colsum,
                                                  float* __restrict__ colsumsq) {
    __shared__ float As[64 * KC];   // 8 KB
    __shared__ float Ws[KC * 128];  // 16 KB
    int tid = threadIdx.x;
    int row0 = blockIdx.x * 64;
    int tx = tid & 31;
    int ty = tid >> 5;

    const float4* a4 = (const float4*)ax;
    const float4* W4 = (const float4*)Wm;
    float4* As4 = (float4*)As;
    float4* Ws4 = (float4*)Ws;

    float acc[8][4] = {};

    for (int kc = 0; kc < 128; kc += KC) {
        __syncthreads();  // previous chunk fully consumed
#pragma unroll
        for (int i = 0; i < 2; ++i) {  // A chunk: 64 rows x 8 float4
            int idx = tid + i * 256;
            int r = idx >> 3;
            int c = idx & 7;
            int gr = row0 + r;
            As4[idx] = (gr < N_NODES) ? a4[(size_t)gr * 32 + (kc >> 2) + c]
                                      : make_float4(0.f, 0.f, 0.f, 0.f);
        }
#pragma unroll
        for (int i = 0; i < 4; ++i) {  // W chunk: 32 rows x 32 float4
            int idx = tid + i * 256;
            Ws4[idx] = W4[(size_t)(kc << 5) + idx];
        }
        __syncthreads();
        for (int k4 = 0; k4 < KC; k4 += 4) {
            float4 a8[8];
#pragma unroll
            for (int r = 0; r < 8; ++r)
                a8[r] = As4[(ty * 8 + r) * 8 + (k4 >> 2)];
#pragma unroll
            for (int kk = 0; kk < 4; ++kk) {
                float4 w = Ws4[(k4 + kk) * 32 + tx];
#pragma unroll
                for (int r = 0; r < 8; ++r) {
                    float av = (kk == 0) ? a8[r].x : (kk == 1) ? a8[r].y
                             : (kk == 2) ? a8[r].z : a8[r].w;
                    acc[r][0] = fmaf(av, w.x, acc[r][0]);
                    acc[r][1] = fmaf(av, w.y, acc[r][1]);
                    acc[r][2] = fmaf(av, w.z, acc[r][2]);
                    acc[r][3] = fmaf(av, w.w, acc[r][3]);
                }
            }
        }
    }

    // write back (in place; own rows only -> race-free)
#pragma unroll
    for (int r = 0; r < 8; ++r) {
        int gr = row0 + ty * 8 + r;
        if (gr < N_NODES)
            ((float4*)&ax[(size_t)gr * 128])[tx] =
                make_float4(acc[r][0], acc[r][1], acc[r][2], acc[r][3]);
    }

    // fused BN column stats; padded rows contribute 0
    float ps[4] = {0.f, 0.f, 0.f, 0.f}, pq[4] = {0.f, 0.f, 0.f, 0.f};
#pragma unroll
    for (int r = 0; r < 8; ++r)
#pragma unroll
        for (int k = 0; k < 4; ++k) {
            float v = acc[r][k];
            ps[k] += v;
            pq[k] += v * v;
        }
    __syncthreads();  // all waves done with As/Ws -> reuse as reduce buffers
#pragma unroll
    for (int k = 0; k < 4; ++k) {
        Ws[ty * 128 + tx * 4 + k] = ps[k];
        As[ty * 128 + tx * 4 + k] = pq[k];
    }
    __syncthreads();
    if (tid < 128) {
        float s = 0.f, q = 0.f;
#pragma unroll
        for (int t = 0; t < 8; ++t) {
            s += Ws[t * 128 + tid];
            q += As[t * 128 + tid];
        }
        atomicAdd(&colsum[tid], s);
        atomicAdd(&colsumsq[tid], q);
    }
}

// ---------------- BN params (b cancels exactly in BatchNorm) ----------------
__global__ void finalize_bn(const float* __restrict__ colsum,
                            const float* __restrict__ colsumsq,
                            const float* __restrict__ gamma,
                            const float* __restrict__ beta,
                            float* __restrict__ scale, float* __restrict__ shift) {
    int c = threadIdx.x;
    float mean = colsum[c] * (1.0f / N_NODES);
    float var = colsumsq[c] * (1.0f / N_NODES) - mean * mean;
    float sc = gamma[c] * rsqrtf(var + BN_EPS);
    scale[c] = sc;
    shift[c] = beta[c] - mean * sc;
}

// ---------------- normalize + ReLU (in place on d_out) ----------------
__global__ __launch_bounds__(256) void normalize_relu(float* __restrict__ out,
                                                      const float* __restrict__ scale,
                                                      const float* __restrict__ shift) {
    const int total = N_NODES * 32;  // float4 count
    float4* o4 = (float4*)out;
    const float4* sc4 = (const float4*)scale;
    const float4* sh4 = (const float4*)shift;
    for (int i = blockIdx.x * blockDim.x + threadIdx.x; i < total;
         i += gridDim.x * blockDim.x) {
        int cg = i & 31;
        float4 v = o4[i];
        float4 sc = sc4[cg];
        float4 sh = sh4[cg];
        v.x = fmaxf(fmaf(v.x, sc.x, sh.x), 0.f);
        v.y = fmaxf(fmaf(v.y, sc.y, sh.y), 0.f);
        v.z = fmaxf(fmaf(v.z, sc.z, sh.z), 0.f);
        v.w = fmaxf(fmaf(v.w, sc.w, sh.w), 0.f);
        o4[i] = v;
    }
}

extern "C" void kernel_launch(void* const* d_in, const int* in_sizes, int n_in,
                              void* d_out, int out_size, void* d_ws, size_t ws_size,
                              hipStream_t stream) {
    const float* x = (const float*)d_in[0];
    const float* Wm = (const float*)d_in[1];
    // d_in[2] = b : cancels exactly in BatchNorm -> unused
    const float* gamma = (const float*)d_in[3];
    const float* beta = (const float*)d_in[4];
    const void* ei = d_in[5];

    float* out = (float*)d_out;  // holds agg_x, then final

    // workspace layout: eb first (8B aligned at base), then int/float arrays
    int2* eb = (int2*)d_ws;                 // E pairs (6.4 MB)
    int* deg = (int*)(eb + N_EDGES);        // N
    int* rp = deg + N_NODES;                // N+1
    int* fp = rp + N_NODES + 1;             // N
    int* bsum = fp + N_NODES;               // 128
    float* dis = (float*)(bsum + 128);      // N
    float* colsum = dis + N_NODES;          // 128
    float* colsumsq = colsum + 128;         // 128
    float* scale = colsumsq + 128;          // 128
    float* shift = scale + 128;             // 128
    int* flag = (int*)(shift + 128);        // 1

    hipMemsetAsync(deg, 0, (size_t)N_NODES * sizeof(int), stream);
    hipMemsetAsync(colsum, 0, 256 * sizeof(float), stream);

    detect_i64<<<1, 256, 0, stream>>>((const unsigned int*)ei, flag);
    count_deg_i<<<2048, 256, 0, stream>>>(ei, flag, deg);
    scan1<<<SCAN_NB, 256, 0, stream>>>(deg, rp, bsum);
    scan2<<<1, 128, 0, stream>>>(bsum, rp);
    scan3<<<(N_NODES + 255) / 256, 256, 0, stream>>>(rp, bsum, fp, deg, dis);
    fill_csr<<<2048, 256, 0, stream>>>(ei, flag, fp, dis, eb);
    gather_x<<<2048, 256, 0, stream>>>(rp, eb, dis, x, out);
    gemm_stats<<<(N_NODES + 63) / 64, 256, 0, stream>>>(out, Wm, colsum, colsumsq);
    finalize_bn<<<1, 128, 0, stream>>>(colsum, colsumsq, gamma, beta, scale, shift);
    normalize_relu<<<2048, 256, 0, stream>>>(out, scale, shift);
}